// Round 3
// baseline (270.639 us; speedup 1.0000x reference)
//
#include <hip/hip_runtime.h>

#define NN 100000
#define NE 1600000
#define ET (NE + NN)
#define NB 391          // buckets of 256 dst nodes
#define CAP 5120        // slots/bucket (mean 4352, +12 sigma)
#define BST 16          // bcnt pad: 64B per counter
#define NTILE (NN/16)   // 6250 gemm tiles

typedef _Float16 f16;
typedef __attribute__((ext_vector_type(8))) _Float16 half8;
typedef __attribute__((ext_vector_type(4))) float f32x4;

__device__ __forceinline__ unsigned short hbits(float v){
    f16 h = (f16)v;
    return *(unsigned short*)&h;
}
// pack 2 f32 -> 2 f16 (round-to-zero) in one v_cvt_pk_rtz instruction
__device__ __forceinline__ unsigned pk16(float a, float b){
    auto p = __builtin_amdgcn_cvt_pkrtz(a, b);   // __fp16 ext_vector(2)
    return *(unsigned*)&p;
}
__device__ __forceinline__ float fast_tanh(float x){
    float e = __expf(2.f*x);
    return 1.f - __fdividef(2.f, e + 1.f);
}
// acc_lo += f16(lo half of h2) * a ; acc_hi += f16(hi half of h2) * a
// v_fma_mix_f32 (VOP3P): op_sel_hi[0]=1 -> src0 is f16; op_sel[0] picks half.
__device__ __forceinline__ void fmix2(float& al, float& ah, unsigned h2, float a){
    asm("v_fma_mix_f32 %0, %2, %3, %0 op_sel_hi:[1,0,0]\n\t"
        "v_fma_mix_f32 %1, %2, %3, %1 op_sel:[1,0,0] op_sel_hi:[1,0,0]"
        : "+v"(al), "+v"(ah) : "v"(h2), "v"(a));
}

// ---------------- CSR build: bin by dst>>8 ----------------
__global__ void __launch_bounds__(256) k_bin(const int* __restrict__ src,
        const int* __restrict__ dst, int* __restrict__ bcnt,
        int* __restrict__ binbuf){
    __shared__ int cnt[NB];
    __shared__ int cur[NB];
    int t = threadIdx.x;
    for(int i=t;i<NB;i+=256) cnt[i]=0;
    __syncthreads();
    int e0 = blockIdx.x*2048;
    #pragma unroll
    for(int k=0;k<8;k++){
        int e = e0 + k*256 + t;
        if(e < ET){ int d = (e < NE) ? dst[e] : (e - NE); atomicAdd(&cnt[d>>8], 1); }
    }
    __syncthreads();
    for(int i=t;i<NB;i+=256){ int c=cnt[i]; cur[i] = c ? atomicAdd(&bcnt[i*BST], c) : 0; }
    __syncthreads();
    #pragma unroll
    for(int k=0;k<8;k++){
        int e = e0 + k*256 + t;
        if(e < ET){
            int s, d;
            if(e < NE){ s = src[e]; d = dst[e]; } else { s = e - NE; d = s; }
            int b = d >> 8;
            int pos = atomicAdd(&cur[b], 1);
            if(pos < CAP) binbuf[b*CAP + pos] = (s << 8) | (d & 255);
        }
    }
}

// ---------------- CSR build: per-bucket dense build (base prefix fused) ----------------
__global__ void __launch_bounds__(256) k_build(const int* __restrict__ bcnt,
        const int* __restrict__ binbuf, int* __restrict__ edge_src,
        int* __restrict__ rowst, int* __restrict__ deg){
    __shared__ int lsrc[CAP];
    __shared__ int ldeg[256], lscan[256], lcur[256], red[256];
    int b = blockIdx.x, t = threadIdx.x;
    int cnt = min(bcnt[b*BST], CAP);
    int part = 0;
    for(int i=t;i<b;i+=256) part += min(bcnt[i*BST], CAP);
    red[t] = part; __syncthreads();
    for(int off=128; off>=1; off>>=1){ if(t<off) red[t]+=red[t+off]; __syncthreads(); }
    int base = red[0];
    __syncthreads();
    ldeg[t] = 0; __syncthreads();
    const int* bb = binbuf + b*CAP;
    for(int i=t;i<cnt;i+=256) atomicAdd(&ldeg[bb[i] & 255], 1);
    __syncthreads();
    int dv = ldeg[t]; lscan[t] = dv; __syncthreads();
    for(int off=1; off<256; off<<=1){
        int u = (t>=off) ? lscan[t-off] : 0;
        __syncthreads(); lscan[t] += u; __syncthreads();
    }
    int excl = lscan[t] - dv; lcur[t] = excl;
    int node = b*256 + t;
    if(node < NN){ rowst[node] = base + excl; deg[node] = dv; }
    __syncthreads();
    for(int i=t;i<cnt;i+=256){
        int ent = bb[i];
        int pos = atomicAdd(&lcur[ent & 255], 1);
        lsrc[pos] = ent >> 8;
    }
    __syncthreads();
    for(int i=t;i<cnt;i+=256) edge_src[base+i] = lsrc[i];
}

// ---------------- h = x@W via f16 MFMA, s_src, s_dst ----------------
// One 16-node tile per wave-iteration. A-frag loaded straight from global
// (lane m=lane&15 reads x[n0+m][kh*32+q*8..+7]); W held as 8 half8 B-frags.
// D layout: col=lane&15, row=(lane>>4)*4+reg (dtype-independent).

template<int FPIN>
__global__ void __launch_bounds__(256) k_gemm(const void* __restrict__ xin,
        const float* __restrict__ W, const float* __restrict__ avs,
        const float* __restrict__ avd, f16* __restrict__ hb,
        float* __restrict__ ssrc, float* __restrict__ sdst){
    int tid = threadIdx.x, lane = tid & 63;
    int col = lane & 15, q = lane >> 4;
    half8 Bf[2][4];
    #pragma unroll
    for(int kh=0;kh<2;kh++){
        #pragma unroll
        for(int nb=0;nb<4;nb++){
            half8 b;
            #pragma unroll
            for(int j=0;j<8;j++){
                float w = W[(kh*32 + q*8 + j)*64 + nb*16 + col];
                b[j] = (f16)w;
            }
            Bf[kh][nb] = b;
        }
    }
    float as[4], ad[4];
    #pragma unroll
    for(int nb=0;nb<4;nb++){ as[nb] = avs[nb*16+col]; ad[nb] = avd[nb*16+col]; }

    int gw = (blockIdx.x*256 + tid) >> 6;
    int nwaves = gridDim.x*4;
    for(int tile = gw; tile < NTILE; tile += nwaves){
        int n0 = tile*16;
        f32x4 acc[4];
        #pragma unroll
        for(int nb=0;nb<4;nb++) acc[nb] = (f32x4){0.f,0.f,0.f,0.f};
        #pragma unroll
        for(int kh=0;kh<2;kh++){
            half8 a;
            if(FPIN){
                const float4* xr = (const float4*)((const float*)xin
                                    + (size_t)(n0+col)*64 + kh*32 + q*8);
                float4 u = xr[0], v = xr[1];
                union { half8 h; uint4 u4; } A;
                A.u4.x = pk16(u.x, u.y);
                A.u4.y = pk16(u.z, u.w);
                A.u4.z = pk16(v.x, v.y);
                A.u4.w = pk16(v.z, v.w);
                a = A.h;
            } else {
                a = *(const half8*)((const f16*)xin
                                    + (size_t)(n0+col)*64 + kh*32 + q*8);
            }
            #pragma unroll
            for(int nb=0;nb<4;nb++)
                acc[nb] = __builtin_amdgcn_mfma_f32_16x16x32_f16(a, Bf[kh][nb], acc[nb], 0,0,0);
        }
        #pragma unroll
        for(int nb=0;nb<4;nb++){
            #pragma unroll
            for(int r=0;r<4;r++)
                hb[(size_t)(n0 + q*4 + r)*64 + nb*16 + col] = (f16)acc[nb][r];
        }
        #pragma unroll
        for(int r=0;r<4;r++){
            float ps = acc[0][r]*as[0] + acc[1][r]*as[1] + acc[2][r]*as[2] + acc[3][r]*as[3];
            float pd = acc[0][r]*ad[0] + acc[1][r]*ad[1] + acc[2][r]*ad[2] + acc[3][r]*ad[3];
            #pragma unroll
            for(int m=8;m>=1;m>>=1){ ps += __shfl_xor(ps,m); pd += __shfl_xor(pd,m); }
            if(col == 0){ ssrc[n0 + q*4 + r] = ps; sdst[n0 + q*4 + r] = pd; }
        }
    }
}

// ---------------- attention + aggregation ----------------
// wave per dst node; 16B/lane gather: uint4 = 8 f16 channels, 8 lanes cover a
// 128B row, 16 edges per iteration (2 loads in flight). LDS (alpha,src) table.
// Per-channel accumulate via v_fma_mix_f32 (f16 src, f32 acc) -> no unpack ops.

template<int LAYER>
__global__ void __launch_bounds__(256) k_agg(
        const int* __restrict__ rowst, const int* __restrict__ deg,
        const int* __restrict__ edge_src,
        const float* __restrict__ ssrc, const float* __restrict__ sdst,
        const f16* __restrict__ hb,
        const float* __restrict__ bias, const float* __restrict__ Wl,
        const float* __restrict__ bl,
        f16* __restrict__ out1b, float* __restrict__ outF){
    __shared__ int2 pairs[256];
    int tid = threadIdx.x;
    int wid  = (blockIdx.x*256 + tid) >> 6;
    int lane = tid & 63;
    if(wid >= NN) return;
    int2* lp = pairs + (tid & 192);      // wave-private 64-entry table
    int rs = rowst[wid];
    int d  = deg[wid];
    float sd = sdst[wid];
    int g8 = lane >> 3;                  // row-group 0..7
    int c  = lane & 7;                   // channel chunk: channels c*8..c*8+7
    float a0=0.f,a1=0.f,a2=0.f,a3=0.f,a4=0.f,a5=0.f,a6=0.f,a7=0.f;

    if(d <= 64){
        int s = 0; float pr = 0.f;
        if(lane < d){
            s = edge_src[rs + lane];
            float t = ssrc[s] + sd;
            t = fmaxf(t, 0.2f*t);            // leaky_relu
            pr = __expf(fminf(t, 80.f));     // no max-shift: logits O(10)
        }
        float sm = pr;
        #pragma unroll
        for(int m=32;m>=1;m>>=1) sm += __shfl_xor(sm,m);
        float alpha = pr * (1.0f/(sm + 1e-16f));
        lp[lane] = make_int2(__float_as_int(alpha), s);   // lanes>=d: alpha=0
        for(int i0=0; i0<d; i0+=16){
            int2 e0 = lp[i0 + g8];
            int2 e1 = lp[i0 + 8 + g8];
            float f0 = __int_as_float(e0.x);
            float f1 = __int_as_float(e1.x);
            uint4 k0 = *(const uint4*)(hb + ((size_t)e0.y<<6) + (c<<3));
            uint4 k1 = *(const uint4*)(hb + ((size_t)e1.y<<6) + (c<<3));
            fmix2(a0,a1,k0.x,f0); fmix2(a2,a3,k0.y,f0);
            fmix2(a4,a5,k0.z,f0); fmix2(a6,a7,k0.w,f0);
            fmix2(a0,a1,k1.x,f1); fmix2(a2,a3,k1.y,f1);
            fmix2(a4,a5,k1.z,f1); fmix2(a6,a7,k1.w,f1);
        }
    } else {
        // generic path (d>64): keep max-shift for safety
        float lmax = -1e30f;
        for(int j=lane; j<d; j+=64){
            int sj = edge_src[rs+j];
            float t = ssrc[sj] + sd;
            lmax = fmaxf(lmax, fmaxf(t, 0.2f*t));
        }
        #pragma unroll
        for(int m=32;m>=1;m>>=1) lmax = fmaxf(lmax, __shfl_xor(lmax,m));
        float lsum = 0.f;
        for(int j=lane; j<d; j+=64){
            int sj = edge_src[rs+j];
            float t = ssrc[sj] + sd;
            lsum += __expf(fmaxf(t, 0.2f*t) - lmax);
        }
        #pragma unroll
        for(int m=32;m>=1;m>>=1) lsum += __shfl_xor(lsum,m);
        float inv = 1.0f/(lsum + 1e-16f);
        for(int cb=0; cb<d; cb+=64){
            int s2 = 0; float al = 0.f;
            int j = cb + lane;
            if(j < d){
                s2 = edge_src[rs+j];
                float t = ssrc[s2] + sd;
                al = __expf(fmaxf(t, 0.2f*t) - lmax) * inv;
            }
            lp[lane] = make_int2(__float_as_int(al), s2);
            int dd = min(d - cb, 64);
            for(int i0=0; i0<dd; i0+=16){
                int2 e0 = lp[i0 + g8];
                int2 e1 = lp[i0 + 8 + g8];
                float f0 = __int_as_float(e0.x);
                float f1 = __int_as_float(e1.x);
                uint4 k0 = *(const uint4*)(hb + ((size_t)e0.y<<6) + (c<<3));
                uint4 k1 = *(const uint4*)(hb + ((size_t)e1.y<<6) + (c<<3));
                fmix2(a0,a1,k0.x,f0); fmix2(a2,a3,k0.y,f0);
                fmix2(a4,a5,k0.z,f0); fmix2(a6,a7,k0.w,f0);
                fmix2(a0,a1,k1.x,f1); fmix2(a2,a3,k1.y,f1);
                fmix2(a4,a5,k1.z,f1); fmix2(a6,a7,k1.w,f1);
            }
        }
    }

    // fold over the 8 row-groups (lane bits 3..5)
    #pragma unroll
    for(int m=32;m>=8;m>>=1){
        a0 += __shfl_xor(a0,m); a1 += __shfl_xor(a1,m);
        a2 += __shfl_xor(a2,m); a3 += __shfl_xor(a3,m);
        a4 += __shfl_xor(a4,m); a5 += __shfl_xor(a5,m);
        a6 += __shfl_xor(a6,m); a7 += __shfl_xor(a7,m);
    }

    const float4* bp = (const float4*)bias;
    float4 bv0 = bp[c*2], bv1 = bp[c*2+1];
    if(LAYER == 1){
        if(g8 == 0){
            uint4 o;
            o.x = (unsigned)hbits(fast_tanh(a0+bv0.x)) | ((unsigned)hbits(fast_tanh(a1+bv0.y))<<16);
            o.y = (unsigned)hbits(fast_tanh(a2+bv0.z)) | ((unsigned)hbits(fast_tanh(a3+bv0.w))<<16);
            o.z = (unsigned)hbits(fast_tanh(a4+bv1.x)) | ((unsigned)hbits(fast_tanh(a5+bv1.y))<<16);
            o.w = (unsigned)hbits(fast_tanh(a6+bv1.z)) | ((unsigned)hbits(fast_tanh(a7+bv1.w))<<16);
            *(uint4*)(out1b + ((size_t)wid<<6) + (c<<3)) = o;
        }
    } else {
        const float4* wp = (const float4*)Wl;
        float4 wv0 = wp[c*2], wv1 = wp[c*2+1];
        float r = (a0+bv0.x)*wv0.x + (a1+bv0.y)*wv0.y + (a2+bv0.z)*wv0.z + (a3+bv0.w)*wv0.w
                + (a4+bv1.x)*wv1.x + (a5+bv1.y)*wv1.y + (a6+bv1.z)*wv1.z + (a7+bv1.w)*wv1.w;
        r += __shfl_xor(r,1); r += __shfl_xor(r,2); r += __shfl_xor(r,4);
        if(lane == 0) outF[wid] = r + bl[0];
    }
}

// ---------------- launch ----------------
extern "C" void kernel_launch(void* const* d_in, const int* in_sizes, int n_in,
                              void* d_out, int out_size, void* d_ws, size_t ws_size,
                              hipStream_t stream) {
    const float* x   = (const float*)d_in[0];
    const int*   ei  = (const int*)d_in[1];
    const float* W1  = (const float*)d_in[2];
    const float* as1 = (const float*)d_in[3];
    const float* ad1 = (const float*)d_in[4];
    const float* b1  = (const float*)d_in[5];
    const float* W2  = (const float*)d_in[6];
    const float* as2 = (const float*)d_in[7];
    const float* ad2 = (const float*)d_in[8];
    const float* b2  = (const float*)d_in[9];
    const float* Wl  = (const float*)d_in[10];
    const float* bl  = (const float*)d_in[11];
    float* out = (float*)d_out;

    const int* srcp = ei;
    const int* dstp = ei + NE;

    char* w = (char*)d_ws;
    int*   edge_src = (int*)w;  w += (size_t)ET*4;      //  6.8 MB
    f16*   hb       = (f16*)w;  w += (size_t)NN*64*2;   // 12.8 MB
    f16*   t1b      = (f16*)w;  w += (size_t)NN*64*2;   // 12.8 MB
    int*   rowst    = (int*)w;  w += (size_t)NN*4;
    int*   deg      = (int*)w;  w += (size_t)NN*4;
    float* ssrc     = (float*)w; w += (size_t)NN*4;
    float* sdst     = (float*)w; w += (size_t)NN*4;
    int*   bcnt     = (int*)w;  w += (size_t)NB*BST*4;
    int*   binbuf   = (int*)hb;     // aliases hb: dead before k_gemm<1> writes

    const int nbBin = (ET + 2047)/2048;     // 831
    const int nbG   = 782;                  // 3128 waves -> ~2 tiles each
    const int nbA   = (NN + 3)/4;           // 25000

    (void)hipMemsetAsync(bcnt, 0, (size_t)NB*BST*4, stream);
    k_bin  <<<nbBin, 256, 0, stream>>>(srcp, dstp, bcnt, binbuf);
    k_build<<<NB,    256, 0, stream>>>(bcnt, binbuf, edge_src, rowst, deg);

    // layer 1
    k_gemm<1><<<nbG, 256, 0, stream>>>((const void*)x, W1, as1, ad1, hb, ssrc, sdst);
    k_agg<1><<<nbA, 256, 0, stream>>>(rowst, deg, edge_src, ssrc, sdst, hb,
                                      b1, (const float*)nullptr, (const float*)nullptr,
                                      t1b, (float*)nullptr);
    // layer 2 + final linear
    k_gemm<0><<<nbG, 256, 0, stream>>>((const void*)t1b, W2, as2, ad2, hb, ssrc, sdst);
    k_agg<2><<<nbA, 256, 0, stream>>>(rowst, deg, edge_src, ssrc, sdst, hb,
                                      b2, Wl, bl,
                                      (f16*)nullptr, out);
}

// Round 4
// 241.951 us; speedup vs baseline: 1.1186x; 1.1186x over previous
//
#include <hip/hip_runtime.h>

#define NN 100000
#define NE 1600000
#define ET (NE + NN)
#define NB 391          // buckets of 256 dst nodes
#define CAP 5120        // slots/bucket (mean 4352, +12 sigma)
#define BST 16          // bcnt pad: 64B per counter
#define NTILE (NN/16)   // 6250 gemm tiles

typedef _Float16 f16;
typedef __attribute__((ext_vector_type(8))) _Float16 half8;
typedef __attribute__((ext_vector_type(4))) float f32x4;

__device__ __forceinline__ unsigned short hbits(float v){
    f16 h = (f16)v;
    return *(unsigned short*)&h;
}
// pack 2 f32 -> 2 f16 (round-to-zero) in one v_cvt_pk_rtz instruction
__device__ __forceinline__ unsigned pk16(float a, float b){
    auto p = __builtin_amdgcn_cvt_pkrtz(a, b);   // __fp16 ext_vector(2)
    return *(unsigned*)&p;
}
__device__ __forceinline__ float fast_tanh(float x){
    float e = __expf(2.f*x);
    return 1.f - __fdividef(2.f, e + 1.f);
}
// acc_lo += f16(lo half of h2) * a ; acc_hi += f16(hi half of h2) * a
__device__ __forceinline__ void fmix2(float& al, float& ah, unsigned h2, float a){
    asm("v_fma_mix_f32 %0, %2, %3, %0 op_sel_hi:[1,0,0]\n\t"
        "v_fma_mix_f32 %1, %2, %3, %1 op_sel:[1,0,0] op_sel_hi:[1,0,0]"
        : "+v"(al), "+v"(ah) : "v"(h2), "v"(a));
}

// ---------------- CSR build: bin by dst>>8 ----------------
__global__ void __launch_bounds__(256) k_bin(const int* __restrict__ src,
        const int* __restrict__ dst, int* __restrict__ bcnt,
        int* __restrict__ binbuf){
    __shared__ int cnt[NB];
    __shared__ int cur[NB];
    int t = threadIdx.x;
    for(int i=t;i<NB;i+=256) cnt[i]=0;
    __syncthreads();
    int e0 = blockIdx.x*2048;
    #pragma unroll
    for(int k=0;k<8;k++){
        int e = e0 + k*256 + t;
        if(e < ET){ int d = (e < NE) ? dst[e] : (e - NE); atomicAdd(&cnt[d>>8], 1); }
    }
    __syncthreads();
    for(int i=t;i<NB;i+=256){ int c=cnt[i]; cur[i] = c ? atomicAdd(&bcnt[i*BST], c) : 0; }
    __syncthreads();
    #pragma unroll
    for(int k=0;k<8;k++){
        int e = e0 + k*256 + t;
        if(e < ET){
            int s, d;
            if(e < NE){ s = src[e]; d = dst[e]; } else { s = e - NE; d = s; }
            int b = d >> 8;
            int pos = atomicAdd(&cur[b], 1);
            if(pos < CAP) binbuf[b*CAP + pos] = (s << 8) | (d & 255);
        }
    }
}

// ---------------- CSR build: per-bucket dense build (base prefix fused) ----------------
__global__ void __launch_bounds__(256) k_build(const int* __restrict__ bcnt,
        const int* __restrict__ binbuf, int* __restrict__ edge_src,
        int* __restrict__ rowst, int* __restrict__ deg){
    __shared__ int lsrc[CAP];
    __shared__ int ldeg[256], lscan[256], lcur[256], red[256];
    int b = blockIdx.x, t = threadIdx.x;
    int cnt = min(bcnt[b*BST], CAP);
    int part = 0;
    for(int i=t;i<b;i+=256) part += min(bcnt[i*BST], CAP);
    red[t] = part; __syncthreads();
    for(int off=128; off>=1; off>>=1){ if(t<off) red[t]+=red[t+off]; __syncthreads(); }
    int base = red[0];
    __syncthreads();
    ldeg[t] = 0; __syncthreads();
    const int* bb = binbuf + b*CAP;
    for(int i=t;i<cnt;i+=256) atomicAdd(&ldeg[bb[i] & 255], 1);
    __syncthreads();
    int dv = ldeg[t]; lscan[t] = dv; __syncthreads();
    for(int off=1; off<256; off<<=1){
        int u = (t>=off) ? lscan[t-off] : 0;
        __syncthreads(); lscan[t] += u; __syncthreads();
    }
    int excl = lscan[t] - dv; lcur[t] = excl;
    int node = b*256 + t;
    if(node < NN){ rowst[node] = base + excl; deg[node] = dv; }
    __syncthreads();
    for(int i=t;i<cnt;i+=256){
        int ent = bb[i];
        int pos = atomicAdd(&lcur[ent & 255], 1);
        lsrc[pos] = ent >> 8;
    }
    __syncthreads();
    for(int i=t;i<cnt;i+=256) edge_src[base+i] = lsrc[i];
}

// ---------------- h = x@W via f16 MFMA, s_src, s_dst ----------------
template<int FPIN>
__global__ void __launch_bounds__(256) k_gemm(const void* __restrict__ xin,
        const float* __restrict__ W, const float* __restrict__ avs,
        const float* __restrict__ avd, f16* __restrict__ hb,
        float* __restrict__ ssrc, float* __restrict__ sdst){
    int tid = threadIdx.x, lane = tid & 63;
    int col = lane & 15, q = lane >> 4;
    half8 Bf[2][4];
    #pragma unroll
    for(int kh=0;kh<2;kh++){
        #pragma unroll
        for(int nb=0;nb<4;nb++){
            half8 b;
            #pragma unroll
            for(int j=0;j<8;j++){
                float w = W[(kh*32 + q*8 + j)*64 + nb*16 + col];
                b[j] = (f16)w;
            }
            Bf[kh][nb] = b;
        }
    }
    float as[4], ad[4];
    #pragma unroll
    for(int nb=0;nb<4;nb++){ as[nb] = avs[nb*16+col]; ad[nb] = avd[nb*16+col]; }

    int gw = (blockIdx.x*256 + tid) >> 6;
    int nwaves = gridDim.x*4;
    for(int tile = gw; tile < NTILE; tile += nwaves){
        int n0 = tile*16;
        f32x4 acc[4];
        #pragma unroll
        for(int nb=0;nb<4;nb++) acc[nb] = (f32x4){0.f,0.f,0.f,0.f};
        #pragma unroll
        for(int kh=0;kh<2;kh++){
            half8 a;
            if(FPIN){
                const float4* xr = (const float4*)((const float*)xin
                                    + (size_t)(n0+col)*64 + kh*32 + q*8);
                float4 u = xr[0], v = xr[1];
                union { half8 h; uint4 u4; } A;
                A.u4.x = pk16(u.x, u.y);
                A.u4.y = pk16(u.z, u.w);
                A.u4.z = pk16(v.x, v.y);
                A.u4.w = pk16(v.z, v.w);
                a = A.h;
            } else {
                a = *(const half8*)((const f16*)xin
                                    + (size_t)(n0+col)*64 + kh*32 + q*8);
            }
            #pragma unroll
            for(int nb=0;nb<4;nb++)
                acc[nb] = __builtin_amdgcn_mfma_f32_16x16x32_f16(a, Bf[kh][nb], acc[nb], 0,0,0);
        }
        #pragma unroll
        for(int nb=0;nb<4;nb++){
            #pragma unroll
            for(int r=0;r<4;r++)
                hb[(size_t)(n0 + q*4 + r)*64 + nb*16 + col] = (f16)acc[nb][r];
        }
        #pragma unroll
        for(int r=0;r<4;r++){
            float ps = acc[0][r]*as[0] + acc[1][r]*as[1] + acc[2][r]*as[2] + acc[3][r]*as[3];
            float pd = acc[0][r]*ad[0] + acc[1][r]*ad[1] + acc[2][r]*ad[2] + acc[3][r]*ad[3];
            #pragma unroll
            for(int m=8;m>=1;m>>=1){ ps += __shfl_xor(ps,m); pd += __shfl_xor(pd,m); }
            if(col == 0){ ssrc[n0 + q*4 + r] = ps; sdst[n0 + q*4 + r] = pd; }
        }
    }
}

// ---------------- full-wave fallback: one node, any degree ----------------
template<int LAYER>
__device__ __forceinline__ void node_full(int node, int lane, int2* lp,
        const int* __restrict__ rowst, const int* __restrict__ deg,
        const int* __restrict__ edge_src, const float* __restrict__ ssrc,
        const float* __restrict__ sdst, const f16* __restrict__ hb,
        const float* __restrict__ bias, const float* __restrict__ Wl,
        const float* __restrict__ bl, f16* __restrict__ out1b,
        float* __restrict__ outF){
    int rs = rowst[node];
    int d  = deg[node];
    float sd = sdst[node];
    int g8 = lane >> 3;
    int c  = lane & 7;
    float a0=0.f,a1=0.f,a2=0.f,a3=0.f,a4=0.f,a5=0.f,a6=0.f,a7=0.f;

    float lmax = -1e30f;
    for(int j=lane; j<d; j+=64){
        int sj = edge_src[rs+j];
        float t = ssrc[sj] + sd;
        lmax = fmaxf(lmax, fmaxf(t, 0.2f*t));
    }
    #pragma unroll
    for(int m=32;m>=1;m>>=1) lmax = fmaxf(lmax, __shfl_xor(lmax,m));
    float lsum = 0.f;
    for(int j=lane; j<d; j+=64){
        int sj = edge_src[rs+j];
        float t = ssrc[sj] + sd;
        lsum += __expf(fmaxf(t, 0.2f*t) - lmax);
    }
    #pragma unroll
    for(int m=32;m>=1;m>>=1) lsum += __shfl_xor(lsum,m);
    float inv = 1.0f/(lsum + 1e-16f);
    for(int cb=0; cb<d; cb+=64){
        int s2 = 0; float al = 0.f;
        int j = cb + lane;
        if(j < d){
            s2 = edge_src[rs+j];
            float t = ssrc[s2] + sd;
            al = __expf(fmaxf(t, 0.2f*t) - lmax) * inv;
        }
        lp[lane] = make_int2(__float_as_int(al), s2);
        int dd = min(d - cb, 64);
        for(int i0=0; i0<dd; i0+=16){
            int2 e0 = lp[i0 + g8];
            int2 e1 = lp[i0 + 8 + g8];
            float f0 = __int_as_float(e0.x);
            float f1 = __int_as_float(e1.x);
            uint4 k0 = *(const uint4*)(hb + ((size_t)e0.y<<6) + (c<<3));
            uint4 k1 = *(const uint4*)(hb + ((size_t)e1.y<<6) + (c<<3));
            fmix2(a0,a1,k0.x,f0); fmix2(a2,a3,k0.y,f0);
            fmix2(a4,a5,k0.z,f0); fmix2(a6,a7,k0.w,f0);
            fmix2(a0,a1,k1.x,f1); fmix2(a2,a3,k1.y,f1);
            fmix2(a4,a5,k1.z,f1); fmix2(a6,a7,k1.w,f1);
        }
    }
    #pragma unroll
    for(int m=32;m>=8;m>>=1){
        a0 += __shfl_xor(a0,m); a1 += __shfl_xor(a1,m);
        a2 += __shfl_xor(a2,m); a3 += __shfl_xor(a3,m);
        a4 += __shfl_xor(a4,m); a5 += __shfl_xor(a5,m);
        a6 += __shfl_xor(a6,m); a7 += __shfl_xor(a7,m);
    }
    const float4* bp = (const float4*)bias;
    float4 bv0 = bp[c*2], bv1 = bp[c*2+1];
    if(LAYER == 1){
        if(g8 == 0){
            uint4 o;
            o.x = (unsigned)hbits(fast_tanh(a0+bv0.x)) | ((unsigned)hbits(fast_tanh(a1+bv0.y))<<16);
            o.y = (unsigned)hbits(fast_tanh(a2+bv0.z)) | ((unsigned)hbits(fast_tanh(a3+bv0.w))<<16);
            o.z = (unsigned)hbits(fast_tanh(a4+bv1.x)) | ((unsigned)hbits(fast_tanh(a5+bv1.y))<<16);
            o.w = (unsigned)hbits(fast_tanh(a6+bv1.z)) | ((unsigned)hbits(fast_tanh(a7+bv1.w))<<16);
            *(uint4*)(out1b + ((size_t)node<<6) + (c<<3)) = o;
        }
    } else {
        const float4* wp = (const float4*)Wl;
        float4 wv0 = wp[c*2], wv1 = wp[c*2+1];
        float r = (a0+bv0.x)*wv0.x + (a1+bv0.y)*wv0.y + (a2+bv0.z)*wv0.z + (a3+bv0.w)*wv0.w
                + (a4+bv1.x)*wv1.x + (a5+bv1.y)*wv1.y + (a6+bv1.z)*wv1.z + (a7+bv1.w)*wv1.w;
        r += __shfl_xor(r,1); r += __shfl_xor(r,2); r += __shfl_xor(r,4);
        if(lane == 0) outF[node] = r + bl[0];
    }
}

// ---------------- attention + aggregation: 2 nodes per wave ----------------
// Fast path (both halves d<=32): 32 lanes per node. Softmax reduce width 32.
// Gather: 4 row-groups x 8 channel-chunks, 8 edges/iter/node via fma_mix.
// Channel-splitting fold: 2 levels, each lane ends with 2 fully-reduced
// channels -> per-lane epilogue (2 tanh on 64 lanes instead of 8x on all).

template<int LAYER>
__global__ void __launch_bounds__(256) k_agg(
        const int* __restrict__ rowst, const int* __restrict__ deg,
        const int* __restrict__ edge_src,
        const float* __restrict__ ssrc, const float* __restrict__ sdst,
        const f16* __restrict__ hb,
        const float* __restrict__ bias, const float* __restrict__ Wl,
        const float* __restrict__ bl,
        f16* __restrict__ out1b, float* __restrict__ outF){
    __shared__ int2 pairs[256];
    int tid = threadIdx.x;
    int wv   = (blockIdx.x*256 + tid) >> 6;   // wave id: 0..NN/2-1
    int lane = tid & 63;
    if(wv*2 >= NN) return;
    int2* lp = pairs + (tid & 192);           // wave-private 64-entry table
    int half = lane >> 5, l = lane & 31;
    int node = wv*2 + half;

    int rs = rowst[node];
    int d  = deg[node];
    float sd = sdst[node];
    int dmax = max(d, __shfl_xor(d, 32));

    if(dmax <= 32){
        // ---- per-half softmax ----
        int s = 0; float pr = 0.f;
        if(l < d){
            s = edge_src[rs + l];
            float t = ssrc[s] + sd;
            t = fmaxf(t, 0.2f*t);            // leaky_relu
            pr = __expf(fminf(t, 80.f));     // no max-shift: logits O(10)
        }
        float sm = pr;
        #pragma unroll
        for(int m=16;m>=1;m>>=1) sm += __shfl_xor(sm,m);
        float alpha = pr * (1.0f/(sm + 1e-16f));
        lp[lane] = make_int2(__float_as_int(alpha), s);   // lane = half*32+l

        // ---- gather: 8 edges/iter per half ----
        int g4 = l >> 3;                     // row-group 0..3
        int c  = l & 7;                      // channel chunk
        int base = half << 5;
        float a0=0.f,a1=0.f,a2=0.f,a3=0.f,a4=0.f,a5=0.f,a6=0.f,a7=0.f;
        for(int i0=0; i0<d; i0+=8){
            int2 e0 = lp[base + i0 + g4];
            int2 e1 = lp[base + i0 + 4 + g4];
            float f0 = __int_as_float(e0.x);
            float f1 = __int_as_float(e1.x);
            uint4 k0 = *(const uint4*)(hb + ((size_t)e0.y<<6) + (c<<3));
            uint4 k1 = *(const uint4*)(hb + ((size_t)e1.y<<6) + (c<<3));
            fmix2(a0,a1,k0.x,f0); fmix2(a2,a3,k0.y,f0);
            fmix2(a4,a5,k0.z,f0); fmix2(a6,a7,k0.w,f0);
            fmix2(a0,a1,k1.x,f1); fmix2(a2,a3,k1.y,f1);
            fmix2(a4,a5,k1.z,f1); fmix2(a6,a7,k1.w,f1);
        }

        // ---- channel-splitting fold over row-groups (lane bits 3,4) ----
        bool b3 = (l >> 3) & 1, b4 = (l >> 4) & 1;
        float u0 = b3 ? a4 : a0, v0 = b3 ? a0 : a4; u0 += __shfl_xor(v0, 8);
        float u1 = b3 ? a5 : a1, v1 = b3 ? a1 : a5; u1 += __shfl_xor(v1, 8);
        float u2 = b3 ? a6 : a2, v2 = b3 ? a2 : a6; u2 += __shfl_xor(v2, 8);
        float u3 = b3 ? a7 : a3, v3 = b3 ? a3 : a7; u3 += __shfl_xor(v3, 8);
        float w0 = b4 ? u2 : u0, z0 = b4 ? u0 : u2; w0 += __shfl_xor(z0, 16);
        float w1 = b4 ? u3 : u1, z1 = b4 ? u1 : u3; w1 += __shfl_xor(z1, 16);
        int ch0 = (c<<3) + ((int)b3<<2) + ((int)b4<<1);   // even; w1 = ch0+1

        if(LAYER == 1){
            float2 bv = ((const float2*)bias)[ch0>>1];
            unsigned o = pk16(fast_tanh(w0 + bv.x), fast_tanh(w1 + bv.y));
            *(unsigned*)(out1b + ((size_t)node<<6) + ch0) = o;
        } else {
            float2 bv = ((const float2*)bias)[ch0>>1];
            float2 wl = ((const float2*)Wl)[ch0>>1];
            float r = (w0 + bv.x)*wl.x + (w1 + bv.y)*wl.y;
            #pragma unroll
            for(int m=16;m>=1;m>>=1) r += __shfl_xor(r,m);
            if(l == 0) outF[node] = r + bl[0];
        }
    } else {
        // rare: a node with d>32 in this pair -> full-wave generic, twice
        node_full<LAYER>(wv*2,   lane, lp, rowst, deg, edge_src, ssrc, sdst,
                         hb, bias, Wl, bl, out1b, outF);
        node_full<LAYER>(wv*2+1, lane, lp, rowst, deg, edge_src, ssrc, sdst,
                         hb, bias, Wl, bl, out1b, outF);
    }
}

// ---------------- launch ----------------
extern "C" void kernel_launch(void* const* d_in, const int* in_sizes, int n_in,
                              void* d_out, int out_size, void* d_ws, size_t ws_size,
                              hipStream_t stream) {
    const float* x   = (const float*)d_in[0];
    const int*   ei  = (const int*)d_in[1];
    const float* W1  = (const float*)d_in[2];
    const float* as1 = (const float*)d_in[3];
    const float* ad1 = (const float*)d_in[4];
    const float* b1  = (const float*)d_in[5];
    const float* W2  = (const float*)d_in[6];
    const float* as2 = (const float*)d_in[7];
    const float* ad2 = (const float*)d_in[8];
    const float* b2  = (const float*)d_in[9];
    const float* Wl  = (const float*)d_in[10];
    const float* bl  = (const float*)d_in[11];
    float* out = (float*)d_out;

    const int* srcp = ei;
    const int* dstp = ei + NE;

    char* w = (char*)d_ws;
    int*   edge_src = (int*)w;  w += (size_t)ET*4;      //  6.8 MB
    f16*   hb       = (f16*)w;  w += (size_t)NN*64*2;   // 12.8 MB
    f16*   t1b      = (f16*)w;  w += (size_t)NN*64*2;   // 12.8 MB
    int*   rowst    = (int*)w;  w += (size_t)NN*4;
    int*   deg      = (int*)w;  w += (size_t)NN*4;
    float* ssrc     = (float*)w; w += (size_t)NN*4;
    float* sdst     = (float*)w; w += (size_t)NN*4;
    int*   bcnt     = (int*)w;  w += (size_t)NB*BST*4;
    int*   binbuf   = (int*)hb;     // aliases hb: dead before k_gemm<1> writes

    const int nbBin = (ET + 2047)/2048;     // 831
    const int nbG   = 782;                  // 3128 waves -> ~2 tiles each
    const int nbA   = (NN/2 + 3)/4;         // 12500: 4 waves/block, 2 nodes/wave

    (void)hipMemsetAsync(bcnt, 0, (size_t)NB*BST*4, stream);
    k_bin  <<<nbBin, 256, 0, stream>>>(srcp, dstp, bcnt, binbuf);
    k_build<<<NB,    256, 0, stream>>>(bcnt, binbuf, edge_src, rowst, deg);

    // layer 1
    k_gemm<1><<<nbG, 256, 0, stream>>>((const void*)x, W1, as1, ad1, hb, ssrc, sdst);
    k_agg<1><<<nbA, 256, 0, stream>>>(rowst, deg, edge_src, ssrc, sdst, hb,
                                      b1, (const float*)nullptr, (const float*)nullptr,
                                      t1b, (float*)nullptr);
    // layer 2 + final linear
    k_gemm<0><<<nbG, 256, 0, stream>>>((const void*)t1b, W2, as2, ad2, hb, ssrc, sdst);
    k_agg<2><<<nbA, 256, 0, stream>>>(rowst, deg, edge_src, ssrc, sdst, hb,
                                      b2, Wl, bl,
                                      (f16*)nullptr, out);
}